// Round 2
// baseline (11.529 us; speedup 1.0000x reference)
//
#include <hip/hip_runtime.h>
#include <math.h>

// SSA loss, fused single-kernel version.
//
//   xn = x / max(||x||_2, 1e-12) per row (dim=1)
//   Frobenius identity: ||a a^T - c c^T||_F^2 = ||a||^4 + ||c||^4 - 2(a.c)^2
//   dist(m,n) = sqrt(1e-12 + sum_b(...)),  ssa[m] = sum_n focal(l_m-l_n)*dist
//   focal(d) = log(0.5 d + 1) if d > 1e-12 else 0
//
// B=128, D=512, fp32. O(B*D) work -> dispatch-latency-bound, so everything
// is fused into ONE kernel node:
//   - 128 blocks x 64 lanes: per-row partials -> ws[pair*128 + b]
//   - release fence + atomicAdd on counter; the last-arriving block
//     (old % 128 == 127, initial-value-agnostic -> poison/replay safe)
//     runs the 384-element epilogue and writes out[3].

#define SSA_BETA      0.5f
#define SSA_THRESHOLD 1e-12f
#define SSA_NORM_EPS  1e-12f
#define SSA_SQRT_EPS  1e-12f

static constexpr int SSA_B = 128;
static constexpr int SSA_D = 512;
// counter lives well past the 384 partial floats (separate cache line)
static constexpr int SSA_CTR_OFS = 512;  // float index into ws

__global__ __launch_bounds__(64) void ssa_fused_kernel(
    const float* __restrict__ xa, const float* __restrict__ xv,
    const float* __restrict__ xt, const float* __restrict__ la,
    const float* __restrict__ lv, const float* __restrict__ lt,
    float* __restrict__ out, float* __restrict__ ws) {
  const int b = blockIdx.x;
  const int lane = threadIdx.x;

  const float4* pa = reinterpret_cast<const float4*>(xa + b * SSA_D);
  const float4* pv = reinterpret_cast<const float4*>(xv + b * SSA_D);
  const float4* pt = reinterpret_cast<const float4*>(xt + b * SSA_D);

  float sa = 0.f, sv = 0.f, st = 0.f;     // squared norms
  float dav = 0.f, dat = 0.f, dvt = 0.f;  // dot products

#pragma unroll
  for (int k = 0; k < 2; ++k) {
    const int idx = lane + 64 * k;  // float4 index within row (0..127)
    const float4 a = pa[idx];
    const float4 v = pv[idx];
    const float4 t = pt[idx];
    sa  += a.x * a.x + a.y * a.y + a.z * a.z + a.w * a.w;
    sv  += v.x * v.x + v.y * v.y + v.z * v.z + v.w * v.w;
    st  += t.x * t.x + t.y * t.y + t.z * t.z + t.w * t.w;
    dav += a.x * v.x + a.y * v.y + a.z * v.z + a.w * v.w;
    dat += a.x * t.x + a.y * t.y + a.z * t.z + a.w * t.w;
    dvt += v.x * t.x + v.y * t.y + v.z * t.z + v.w * t.w;
  }

  // Butterfly reduction across the 64-lane wave.
#pragma unroll
  for (int off = 32; off > 0; off >>= 1) {
    sa  += __shfl_xor(sa, off);
    sv  += __shfl_xor(sv, off);
    st  += __shfl_xor(st, off);
    dav += __shfl_xor(dav, off);
    dat += __shfl_xor(dat, off);
    dvt += __shfl_xor(dvt, off);
  }

  if (lane == 0) {
    const float na = fmaxf(sqrtf(sa), SSA_NORM_EPS);
    const float nv = fmaxf(sqrtf(sv), SSA_NORM_EPS);
    const float nt = fmaxf(sqrtf(st), SSA_NORM_EPS);
    const float na2 = sa / (na * na);  // ||a_norm||^2 (== 1 up to rounding)
    const float nv2 = sv / (nv * nv);
    const float nt2 = st / (nt * nt);
    const float cav  = dav / (na * nv);  // normalized dots
    const float cat_ = dat / (na * nt);
    const float cvt_ = dvt / (nv * nt);
    ws[0 * SSA_B + b] = na2 * na2 + nv2 * nv2 - 2.f * cav  * cav;
    ws[1 * SSA_B + b] = na2 * na2 + nt2 * nt2 - 2.f * cat_ * cat_;
    ws[2 * SSA_B + b] = nv2 * nv2 + nt2 * nt2 - 2.f * cvt_ * cvt_;
  }

  // Release: make this block's ws stores visible device-wide (agent-scope
  // fence -> L2 writeback on gfx950, covers cross-XCD).
  __threadfence();

  unsigned int old = 0;
  if (lane == 0) {
    old = atomicAdd(reinterpret_cast<unsigned int*>(ws + SSA_CTR_OFS), 1u);
  }
  old = __shfl(old, 0);
  // The 128 increments of one call sweep 128 consecutive residues mod 128,
  // so exactly one block sees residue 127 regardless of the counter's
  // initial (poisoned / accumulated) value. That block is the last arriver.
  if ((old & 127u) != 127u) return;

  // Acquire: invalidate caches so we see all other blocks' partials.
  __threadfence();

  float s0 = ws[0 * SSA_B + lane] + ws[0 * SSA_B + lane + 64];
  float s1 = ws[1 * SSA_B + lane] + ws[1 * SSA_B + lane + 64];
  float s2 = ws[2 * SSA_B + lane] + ws[2 * SSA_B + lane + 64];

#pragma unroll
  for (int off = 32; off > 0; off >>= 1) {
    s0 += __shfl_xor(s0, off);
    s1 += __shfl_xor(s1, off);
    s2 += __shfl_xor(s2, off);
  }

  if (lane == 0) {
    const float dist01 = sqrtf(SSA_SQRT_EPS + s0);  // (audio, video)
    const float dist02 = sqrtf(SSA_SQRT_EPS + s1);  // (audio, text)
    const float dist12 = sqrtf(SSA_SQRT_EPS + s2);  // (video, text)

    const float loss[3] = {la[0], lv[0], lt[0]};
    const float dist[3][3] = {{0.f, dist01, dist02},
                              {dist01, 0.f, dist12},
                              {dist02, dist12, 0.f}};
#pragma unroll
    for (int m = 0; m < 3; ++m) {
      float acc = 0.f;
#pragma unroll
      for (int n = 0; n < 3; ++n) {
        if (n == m) continue;
        const float d = loss[m] - loss[n];
        const float focal = (d > SSA_THRESHOLD) ? logf(SSA_BETA * d + 1.0f) : 0.f;
        acc += focal * dist[m][n];
      }
      out[m] = acc;
    }
  }
}

extern "C" void kernel_launch(void* const* d_in, const int* in_sizes, int n_in,
                              void* d_out, int out_size, void* d_ws, size_t ws_size,
                              hipStream_t stream) {
  const float* xa = (const float*)d_in[0];
  const float* xv = (const float*)d_in[1];
  const float* xt = (const float*)d_in[2];
  const float* la = (const float*)d_in[3];
  const float* lv = (const float*)d_in[4];
  const float* lt = (const float*)d_in[5];
  float* out = (float*)d_out;
  float* ws = (float*)d_ws;  // uses 512 floats partials/pad + 1 uint counter

  ssa_fused_kernel<<<SSA_B, 64, 0, stream>>>(xa, xv, xt, la, lv, lt, out, ws);
}

// Round 3
// 9.753 us; speedup vs baseline: 1.1820x; 1.1820x over previous
//
#include <hip/hip_runtime.h>
#include <math.h>

// SSA loss, fused single-kernel, short-sweep version.
//
//   xn = x / max(||x||_2, 1e-12) per row (dim=1)
//   Frobenius identity: ||a a^T - c c^T||_F^2 = ||a||^4 + ||c||^4 - 2(a.c)^2
//   dist(m,n) = sqrt(1e-12 + sum_b(...)),  ssa[m] = sum_n focal(l_m-l_n)*dist
//   focal(d) = log(0.5 d + 1) if d > 1e-12 else 0
//
// B=128, D=512, fp32. Dispatch/replay-overhead-bound (~10us fixed floor,
// R1 two-node == R2 one-node == 11.4-11.5us). This round minimizes the
// in-kernel serial tail: 32 blocks x 256 threads (1 wave per row, 4 rows
// per block), LDS combine -> ONE ws writer + ONE atomic per block.
// Atomic sweep 128 -> 32, epilogue loads 384 -> 96 floats.

#define SSA_BETA      0.5f
#define SSA_THRESHOLD 1e-12f
#define SSA_NORM_EPS  1e-12f
#define SSA_SQRT_EPS  1e-12f

static constexpr int SSA_B = 128;
static constexpr int SSA_D = 512;
static constexpr int SSA_NBLK = 32;      // blocks; 4 rows (waves) each
static constexpr int SSA_CTR_OFS = 512;  // float index of counter in ws

__global__ __launch_bounds__(256) void ssa_fused_kernel(
    const float* __restrict__ xa, const float* __restrict__ xv,
    const float* __restrict__ xt, const float* __restrict__ la,
    const float* __restrict__ lv, const float* __restrict__ lt,
    float* __restrict__ out, float* __restrict__ ws) {
  const int tid = threadIdx.x;
  const int wave = tid >> 6;
  const int lane = tid & 63;
  const int b = blockIdx.x * 4 + wave;  // row handled by this wave

  const float4* pa = reinterpret_cast<const float4*>(xa + b * SSA_D);
  const float4* pv = reinterpret_cast<const float4*>(xv + b * SSA_D);
  const float4* pt = reinterpret_cast<const float4*>(xt + b * SSA_D);

  float sa = 0.f, sv = 0.f, st = 0.f;     // squared norms
  float dav = 0.f, dat = 0.f, dvt = 0.f;  // dot products

#pragma unroll
  for (int k = 0; k < 2; ++k) {
    const int idx = lane + 64 * k;  // float4 index within row (0..127)
    const float4 a = pa[idx];
    const float4 v = pv[idx];
    const float4 t = pt[idx];
    sa  += a.x * a.x + a.y * a.y + a.z * a.z + a.w * a.w;
    sv  += v.x * v.x + v.y * v.y + v.z * v.z + v.w * v.w;
    st  += t.x * t.x + t.y * t.y + t.z * t.z + t.w * t.w;
    dav += a.x * v.x + a.y * v.y + a.z * v.z + a.w * v.w;
    dat += a.x * t.x + a.y * t.y + a.z * t.z + a.w * t.w;
    dvt += v.x * t.x + v.y * t.y + v.z * t.z + v.w * t.w;
  }

  // Butterfly reduction across the 64-lane wave.
#pragma unroll
  for (int off = 32; off > 0; off >>= 1) {
    sa  += __shfl_xor(sa, off);
    sv  += __shfl_xor(sv, off);
    st  += __shfl_xor(st, off);
    dav += __shfl_xor(dav, off);
    dat += __shfl_xor(dat, off);
    dvt += __shfl_xor(dvt, off);
  }

  __shared__ float sm[3][4];
  if (lane == 0) {
    const float na = fmaxf(sqrtf(sa), SSA_NORM_EPS);
    const float nv = fmaxf(sqrtf(sv), SSA_NORM_EPS);
    const float nt = fmaxf(sqrtf(st), SSA_NORM_EPS);
    const float na2 = sa / (na * na);  // ||a_norm||^2 (== 1 up to rounding)
    const float nv2 = sv / (nv * nv);
    const float nt2 = st / (nt * nt);
    const float cav  = dav / (na * nv);  // normalized dots
    const float cat_ = dat / (na * nt);
    const float cvt_ = dvt / (nv * nt);
    sm[0][wave] = na2 * na2 + nv2 * nv2 - 2.f * cav  * cav;
    sm[1][wave] = na2 * na2 + nt2 * nt2 - 2.f * cat_ * cat_;
    sm[2][wave] = nv2 * nv2 + nt2 * nt2 - 2.f * cvt_ * cvt_;
  }
  __syncthreads();

  // Waves 1-3 are done; wave 0 finishes the block and (maybe) the epilogue.
  if (wave != 0) return;

  unsigned int old = 0;
  if (lane == 0) {
    // Per-block partials, deterministic fixed-order sums.
    ws[0 * SSA_NBLK + blockIdx.x] = sm[0][0] + sm[0][1] + sm[0][2] + sm[0][3];
    ws[1 * SSA_NBLK + blockIdx.x] = sm[1][0] + sm[1][1] + sm[1][2] + sm[1][3];
    ws[2 * SSA_NBLK + blockIdx.x] = sm[2][0] + sm[2][1] + sm[2][2] + sm[2][3];
    // Release: make this block's ws stores visible device-wide.
    __threadfence();
    old = atomicAdd(reinterpret_cast<unsigned int*>(ws + SSA_CTR_OFS), 1u);
  }
  old = __shfl(old, 0);
  // The 32 increments of one call sweep 32 consecutive residues mod 32, so
  // exactly one block sees residue 31 regardless of the counter's initial
  // (poisoned / accumulated) value. That block is the last arriver.
  if ((old & 31u) != 31u) return;

  // Acquire: see all other blocks' partials.
  __threadfence();

  float s0 = 0.f, s1 = 0.f, s2 = 0.f;
  if (lane < SSA_NBLK) {
    s0 = ws[0 * SSA_NBLK + lane];
    s1 = ws[1 * SSA_NBLK + lane];
    s2 = ws[2 * SSA_NBLK + lane];
  }
  // Lanes 0-31 are closed under xor with offsets 16..1.
#pragma unroll
  for (int off = 16; off > 0; off >>= 1) {
    s0 += __shfl_xor(s0, off);
    s1 += __shfl_xor(s1, off);
    s2 += __shfl_xor(s2, off);
  }

  if (lane == 0) {
    const float dist01 = sqrtf(SSA_SQRT_EPS + s0);  // (audio, video)
    const float dist02 = sqrtf(SSA_SQRT_EPS + s1);  // (audio, text)
    const float dist12 = sqrtf(SSA_SQRT_EPS + s2);  // (video, text)

    const float loss[3] = {la[0], lv[0], lt[0]};
    const float dist[3][3] = {{0.f, dist01, dist02},
                              {dist01, 0.f, dist12},
                              {dist02, dist12, 0.f}};
#pragma unroll
    for (int m = 0; m < 3; ++m) {
      float acc = 0.f;
#pragma unroll
      for (int n = 0; n < 3; ++n) {
        if (n == m) continue;
        const float d = loss[m] - loss[n];
        const float focal = (d > SSA_THRESHOLD) ? logf(SSA_BETA * d + 1.0f) : 0.f;
        acc += focal * dist[m][n];
      }
      out[m] = acc;
    }
  }
}

extern "C" void kernel_launch(void* const* d_in, const int* in_sizes, int n_in,
                              void* d_out, int out_size, void* d_ws, size_t ws_size,
                              hipStream_t stream) {
  const float* xa = (const float*)d_in[0];
  const float* xv = (const float*)d_in[1];
  const float* xt = (const float*)d_in[2];
  const float* la = (const float*)d_in[3];
  const float* lv = (const float*)d_in[4];
  const float* lt = (const float*)d_in[5];
  float* out = (float*)d_out;
  float* ws = (float*)d_ws;  // 96 partial floats + pad + 1 uint counter

  ssa_fused_kernel<<<SSA_NBLK, 256, 0, stream>>>(xa, xv, xt, la, lv, lt, out, ws);
}